// Round 1
// 160.372 us; speedup vs baseline: 1.1799x; 1.1799x over previous
//
#include <hip/hip_runtime.h>
#include <math.h>

#define NN 500
#define NE 64
#define BATCH 8
#define RR 15
#define PW 31            // 2R+1
#define CAN 200
#define OHW 198
#define TWO_PI_F 6.28318530717958647692f
// k_setup must cover canvas (320000) + psf_sums (64) + kern (49) AND NN*NN.
#define SETUP_N (BATCH * CAN * CAN + NE + 49)

// --- MFMA prop-rows parameters ---------------------------------------------
// kappa = 2u + p (p=0 re, p=1 im), u padded 500->512 => K = 1024 = 8 chunks x 128
#define BCH 8                      // K-chunks
#define BKC 128                    // kappa per chunk
#define BSTR 136                   // padded row stride (f16 elems; 272 B = 17*16)
#define BG_CHUNK (2 * 64 * BSTR)   // f16 elems per chunk (hi plane + lo plane)
#define ASCALE (1.0f / 64.0f)      // A pre-scale (f16 range safety); undone in k_prop_cols

using f16x8 = __attribute__((ext_vector_type(8))) _Float16;
using f32x4 = __attribute__((ext_vector_type(4))) float;

// Fast accurate sincos for |theta| up to ~1200 rad: Cody-Waite 2-term
// reduction + hardware v_sin/v_cos on the reduced |r| <= pi argument.
__device__ __forceinline__ void fast_sincos_red(float theta, float* s, float* c) {
    const float INV2PI = 0.15915494309189535f;
    const float PI2_HI = 6.28318548202514648f;   // f32(2*pi)
    const float PI2_LO = -1.7484556e-7f;         // 2*pi - PI2_HI
    float n = rintf(theta * INV2PI);
    float r = fmaf(n, -PI2_HI, theta);
    r = fmaf(n, -PI2_LO, r);
    *s = __sinf(r);
    *c = __cosf(r);
}

// ---------------------------------------------------------------------------
// K_setup: K*GAMMA table (f64 sqrt path), 500-pt twiddle table, blur-kernel
// coefficients, canvas+psf_sums zero. GRID MUST COVER SETUP_N.
// ---------------------------------------------------------------------------
__global__ void k_setup(const float* __restrict__ std_u,
                        float* __restrict__ kgamma,
                        float2* __restrict__ tw,
                        float* __restrict__ kern,
                        float* __restrict__ canvas,
                        float* __restrict__ psf_sums) {
    int idx = blockIdx.x * blockDim.x + threadIdx.x;
    if (idx < NN) {
        double th = 2.0 * M_PI * (double)idx / (double)NN;
        tw[idx] = make_float2((float)cos(th), (float)sin(th));
    }
    if (idx < BATCH * CAN * CAN) canvas[idx] = 0.f;
    if (idx >= BATCH * CAN * CAN && idx < BATCH * CAN * CAN + NE)
        psf_sums[idx - BATCH * CAN * CAN] = 0.f;
    if (idx >= BATCH * CAN * CAN + NE && idx < SETUP_N) {
        int t = idx - (BATCH * CAN * CAN + NE);
        float stdv = 0.8f + 0.4f * std_u[0];
        float s2 = stdv * stdv;
        int a = t / 7 - 3, b = t % 7 - 3;
        float g = (float)exp(-0.5 * (double)(a * a + b * b));
        kern[t] = (1.0f / (2.0f * (float)M_PI * s2)) * powf(g, 1.0f / s2);
    }
    if (idx >= NN * NN) return;
    int i = idx / NN, j = idx % NN;
    double fy = (double)((i < 250) ? i : i - 500) * 2000.0;
    double fx = (double)((j < 250) ? j : j - 500) * 2000.0;
    double a = 5.32e-7 * fx;
    double b = 5.32e-7 * fy;
    double g = 1.0 - a * a - b * b;
    g = (g > 0.0) ? sqrt(g) : 0.0;
    float Kf = (float)(2.0 * M_PI * 1.0 / 5.32e-7);
    kgamma[idx] = Kf * (float)g;
}

// ---------------------------------------------------------------------------
// k_setup_b: precompute the partial-IDFT twiddle matrix B in f16 hi/lo split,
// fragment-friendly layout for mfma_f32_16x16x32_f16:
//   B[kappa][nu]: kappa = 2u+p, nu = 2*(r-235)+q (q=0 re-col, q=1 im-col)
//     q=0: p=0 ->  W.re   p=1 -> -W.im
//     q=1: p=0 ->  W.im   p=1 ->  W.re        (W = e^{+2pi i u r / 500})
// Stored [chunk][hi/lo][nu=64][BSTR=136 kappa-local] (272-B padded rows:
// dword stride 68 == 4 (mod 32) => within-16-lane b128 reads are 2-way = free).
// ---------------------------------------------------------------------------
__global__ void k_setup_b(_Float16* __restrict__ Bg) {
    int idx = blockIdx.x * blockDim.x + threadIdx.x;   // (c, nu, j)
    if (idx >= BCH * 64 * BSTR) return;
    int c = idx / (64 * BSTR);
    int rem = idx % (64 * BSTR);
    int nu = rem / BSTR, j = rem % BSTR;
    float hi = 0.f, lo = 0.f;
    int kap = c * BKC + j;
    if (j < BKC && kap < 2 * NN) {
        int u = kap >> 1, p = kap & 1;
        int ri = nu >> 1, q = nu & 1;
        int r = 235 + ri;                 // ri=31 -> dummy col pair (discarded)
        int m = (u * r) % NN;
        double th = 2.0 * M_PI * (double)m / (double)NN;
        double wre = cos(th), wim = sin(th);
        double val = (q == 0) ? ((p == 0) ? wre : -wim)
                              : ((p == 0) ? wim : wre);
        float x = (float)val;
        _Float16 h = (_Float16)x;
        hi = (float)h;
        lo = x - (float)h;
    }
    size_t base = (size_t)c * BG_CHUNK + (size_t)nu * BSTR + j;
    Bg[base] = (_Float16)hi;                    // hi plane
    Bg[base + (size_t)64 * BSTR] = (_Float16)lo;  // lo plane
}

// ---------------------------------------------------------------------------
// 500-pt forward DFT via Cooley-Tukey 20x25. Shared stages helper.
// ---------------------------------------------------------------------------
__device__ __forceinline__ void ct_dft_stages(const float2* xs, const float2* tts,
                                              float2* S, int t,
                                              float2* out1, float2* out2, int* kout) {
    if (t < 250) {
        int d = t / 25;
        int b = t % 25;
        float2 st = tts[(25 * d) % NN];
        float wr = 1.f, wi = 0.f;
        float Er = 0.f, Ei = 0.f, Or_ = 0.f, Oi = 0.f;
#pragma unroll
        for (int a = 0; a < 20; a += 2) {
            float2 x0 = xs[25 * a + b];
            Er += x0.x * wr - x0.y * wi;
            Ei += x0.x * wi + x0.y * wr;
            float nr = wr * st.x - wi * st.y;
            float ni = wr * st.y + wi * st.x;
            float2 x1 = xs[25 * (a + 1) + b];
            Or_ += x1.x * nr - x1.y * ni;
            Oi  += x1.x * ni + x1.y * nr;
            wr = nr * st.x - ni * st.y;
            wi = nr * st.y + ni * st.x;
        }
        S[b * 21 + d]      = make_float2(Er + Or_, Ei + Oi);
        S[b * 21 + d + 10] = make_float2(Er - Or_, Ei - Oi);
    }
    __syncthreads();
    if (t < 250) {
        int k = t;
        int d1 = k % 20;
        int d2 = (d1 + 10) % 20;
        float2 s1 = tts[k];
        float wr = 1.f, wi = 0.f;
        float a1r = 0.f, a1i = 0.f, a2r = 0.f, a2i = 0.f;
#pragma unroll
        for (int b = 0; b < 25; ++b) {
            float2 u1 = S[b * 21 + d1];
            float2 u2 = S[b * 21 + d2];
            a1r += u1.x * wr - u1.y * wi;
            a1i += u1.x * wi + u1.y * wr;
            float sgnb = (b & 1) ? -1.f : 1.f;
            float w2r = sgnb * wr, w2i = sgnb * wi;
            a2r += u2.x * w2r - u2.y * w2i;
            a2i += u2.x * w2i + u2.y * w2r;
            float nr = wr * s1.x - wi * s1.y;
            wi = wr * s1.y + wi * s1.x;
            wr = nr;
        }
        *out1 = make_float2(a1r, a1i);
        *out2 = make_float2(a2r, a2i);
        *kout = k;
    }
}

// k_dft_rows: fused pupil-field generation (f32) + row DFT; writes R1T[k][y].
__global__ void k_dft_rows(const float* __restrict__ phase, float2* __restrict__ dst,
                           const float2* __restrict__ tw) {
    __shared__ __align__(16) float2 xs[NN];
    __shared__ float2 tts[NN];
    __shared__ float2 S[25 * 21];
    int line = blockIdx.x;                 // y index i
    int t = threadIdx.x;
    const float INV2SIG = 2.2222222e7f;              // 1/(2*(1.5e-4)^2)
    const float C1M = (float)(M_PI / 5.32e-8);       // pi/(WL*FL)
    float y = (float)(line - 250) * 1e-6f;
    float y2 = y * y;
    const float* prow = phase + (size_t)line * NN;
    for (int n = t; n < NN; n += 256) {
        float x = (float)(n - 250) * 1e-6f;
        float r2 = x * x + y2;
        float inc = __expf(-r2 * INV2SIG);
        float c1 = C1M * r2;
        float b1r = __cosf(c1), b1i = -__sinf(c1);
        float ph = prow[n];
        float sp = __sinf(ph), cp = __cosf(ph);
        float ar = inc * cp, ai = inc * sp;
        xs[n] = make_float2(ar * b1r - ai * b1i, ar * b1i + ai * b1r);
        float2 tt = tw[n];
        tts[n] = make_float2(tt.x, -tt.y);   // forward
    }
    __syncthreads();
    float2 o1, o2; int k;
    ct_dft_stages(xs, tts, S, t, &o1, &o2, &k);
    if (t < 250) {
        dst[(size_t)k * NN + line] = o1;           // R1T[k][y]
        dst[(size_t)(k + 250) * NN + line] = o2;
    }
}

__global__ void k_dft_cols(const float2* __restrict__ src, float2* __restrict__ dst,
                           const float2* __restrict__ tw) {
    __shared__ __align__(16) float2 xs[NN];
    __shared__ float2 tts[NN];
    __shared__ float2 S[25 * 21];
    int line = blockIdx.x;                 // kx
    const float2* s = src + (size_t)line * NN;     // R1T row kx, contiguous
    int t = threadIdx.x;
    for (int n = t; n < NN; n += 256) {
        xs[n] = s[n];
        float2 tt = tw[n];
        tts[n] = make_float2(tt.x, -tt.y);
    }
    __syncthreads();
    float2 o1, o2; int k;
    ct_dft_stages(xs, tts, S, t, &o1, &o2, &k);
    if (t < 250) {
        float2* dp = dst + (size_t)line * NN;      // EfT[kx][*], contiguous
        dp[k] = o1;
        dp[k + 250] = o2;
    }
}

// ---------------------------------------------------------------------------
// k_prop_mfma (replaces k_prop_rows): per v, the partial inverse row-DFT is a
// real GEMM  C[64 z][64 nu] = A[64][1024 kappa] x B[1024][64]  run on MFMA
// with f16 hi/lo 3-term split (a*b ~= ah*bh + al*bh + ah*bl, err ~2^-22 rel).
//   A[z][2u+p] = {Re,Im}( EfT[v][u] * e^{i kg[v][u] z_z} ) * (1/64)
// Each lane computes ITS OWN A-fragment elements directly in registers:
// A-frag: row = lane&15 (=> z = w*16 + (lane&15)), kappa = kstep*32+(lane>>4)*8+e
// — no A staging, no transpose, every (z,u) modulated exactly once per block.
// B staged per-K-chunk from precomputed global (L2-resident, 272 KB total).
// C layout (m89-verified): col = lane&15, row = (lane>>4)*4 + reg.
// ---------------------------------------------------------------------------
__global__ void __launch_bounds__(256, 4)
k_prop_mfma(const float2* __restrict__ EfT,
            const float* __restrict__ kgamma,
            const float* __restrict__ zs,
            const _Float16* __restrict__ Bg,
            float2* __restrict__ part) {
    __shared__ __align__(16) _Float16 Bbuf[2][64 * BSTR];  // 34816 B
    __shared__ __align__(16) float2 eft[512];              // 4096 B
    __shared__ __align__(16) float kgs[512];               // 2048 B
    int v = blockIdx.x;
    int t = threadIdx.x;
    int w = t >> 6;                  // wave id 0..3 -> m-tile (z 16w..16w+15)
    int lane = t & 63;
    int lrow = lane & 15;            // A-row / B-col within tile
    int grp = lane >> 4;             // kappa-group 0..3

    for (int n = t; n < 512; n += 256) {
        if (n < NN) {
            eft[n] = EfT[(size_t)v * NN + n];
            kgs[n] = kgamma[(size_t)v * NN + n];
        } else {
            eft[n] = make_float2(0.f, 0.f);
            kgs[n] = 0.f;
        }
    }
    float zv = zs[w * 16 + lrow];    // z of this lane's A rows

    f32x4 acc[4] = {};               // 4 n-tiles (nu = nt*16 + lrow)

#define MODSPLIT(ex, ey, kgv, i0) do {                                        \
        float s_, c_;                                                         \
        fast_sincos_red((kgv) * zv, &s_, &c_);                                \
        float yr = ((ex) * c_ - (ey) * s_) * ASCALE;                          \
        float yi = ((ex) * s_ + (ey) * c_) * ASCALE;                          \
        _Float16 h0 = (_Float16)yr;                                           \
        ah[i0] = h0; al[i0] = (_Float16)(yr - (float)h0);                     \
        _Float16 h1 = (_Float16)yi;                                           \
        ah[i0 + 1] = h1; al[i0 + 1] = (_Float16)(yi - (float)h1);             \
    } while (0)

    for (int c = 0; c < BCH; ++c) {
        __syncthreads();             // prior chunk's B reads complete
        // stage B chunk (hi+lo planes, 34816 B) via reg copy
        const float4* src = (const float4*)(Bg + (size_t)c * BG_CHUNK);
        float4* dst = (float4*)(&Bbuf[0][0]);
        for (int q2 = t; q2 < BG_CHUNK / 8; q2 += 256)
            dst[q2] = src[q2];
        __syncthreads();

#pragma unroll
        for (int sl = 0; sl < 4; ++sl) {
            int s = c * 4 + sl;              // global K-step 0..31
            int u0 = s * 16 + grp * 4;       // this lane's 4 u's
            float4 e01 = *(const float4*)&eft[u0];
            float4 e23 = *(const float4*)&eft[u0 + 2];
            float4 kg4 = *(const float4*)&kgs[u0];
            f16x8 ah, al;
            MODSPLIT(e01.x, e01.y, kg4.x, 0);
            MODSPLIT(e01.z, e01.w, kg4.y, 2);
            MODSPLIT(e23.x, e23.y, kg4.z, 4);
            MODSPLIT(e23.z, e23.w, kg4.w, 6);
            int koff = sl * 32 + grp * 8;
#pragma unroll
            for (int nt = 0; nt < 4; ++nt) {
                int nu = nt * 16 + lrow;
                f16x8 bh = *(const f16x8*)&Bbuf[0][nu * BSTR + koff];
                f16x8 bl = *(const f16x8*)&Bbuf[1][nu * BSTR + koff];
                acc[nt] = __builtin_amdgcn_mfma_f32_16x16x32_f16(ah, bh, acc[nt], 0, 0, 0);
                acc[nt] = __builtin_amdgcn_mfma_f32_16x16x32_f16(al, bh, acc[nt], 0, 0, 0);
                acc[nt] = __builtin_amdgcn_mfma_f32_16x16x32_f16(ah, bl, acc[nt], 0, 0, 0);
            }
        }
    }
#undef MODSPLIT

    // epilogue: C[z][nu] -> part[z][ri][v].{x,y};  nu = 2*ri + q
    float* pf = (float*)part;
#pragma unroll
    for (int nt = 0; nt < 4; ++nt) {
        int nu = nt * 16 + lrow;
        int ri = nu >> 1, q = nu & 1;
        if (ri < PW) {
#pragma unroll
            for (int rg = 0; rg < 4; ++rg) {
                int z = w * 16 + grp * 4 + rg;
                pf[(((size_t)z * PW + ri) * NN + v) * 2 + q] = acc[nt][rg];
            }
        }
    }
}

// ---------------------------------------------------------------------------
// B2: per (r,z): psf[z][r][c] = |inv * sum_v part[z][r][v] W^{vc}|^2,
// c = 235..265. Contiguous psf writes + per-block sum into psf_sums[z].
// inv carries the 1/64 A-scale compensation from k_prop_mfma.
// ---------------------------------------------------------------------------
__global__ void k_prop_cols(const float2* __restrict__ part,
                            float* __restrict__ psf,
                            float* __restrict__ psf_sums) {
    __shared__ float2 X[NN];
    __shared__ float sred[PW];
    int r = blockIdx.x;    // 31
    int z = blockIdx.y;    // 64
    int t = threadIdx.x;
    const float2* col = part + ((size_t)z * PW + r) * NN;
    for (int v = t; v < NN; v += 256) X[v] = col[v];
    __syncthreads();
    if (t < PW * 8) {
        int ci = t >> 3, seg = t & 7;
        int c = 235 + ci;
        float wr, wi, sr, si;
        {
            float th0 = (TWO_PI_F / NN) * (float)((seg * c) % NN);
            sincosf(th0, &wi, &wr);
            float ths = (TWO_PI_F / NN) * (float)((8 * c) % NN);
            sincosf(ths, &si, &sr);
        }
        float ar = 0.f, ai = 0.f;
        for (int v = seg; v < NN; v += 8) {
            float2 xv = X[v];
            ar += xv.x * wr - xv.y * wi;
            ai += xv.x * wi + xv.y * wr;
            float nwr = wr * sr - wi * si;
            wi = wr * si + wi * sr;
            wr = nwr;
        }
#pragma unroll
        for (int m = 1; m < 8; m <<= 1) {
            ar += __shfl_xor(ar, m);
            ai += __shfl_xor(ai, m);
        }
        if (seg == 0 && ci < PW) {
            const float inv = 64.0f / 250000.0f;   // 1/250000 * 64 (A-scale undo)
            float re = ar * inv, im = ai * inv;
            float val = re * re + im * im;
            psf[(size_t)z * (PW * PW) + r * PW + ci] = val;
            sred[ci] = val;
        }
    }
    __syncthreads();
    if (t == 0) {
        float s = 0.f;
#pragma unroll
        for (int i = 0; i < PW; ++i) s += sred[i];
        atomicAdd(&psf_sums[z], s);
    }
}

// ---------------------------------------------------------------------------
__global__ void k_scatter(const float* __restrict__ psf,
                          const float* __restrict__ psf_sums,
                          const int* __restrict__ xyz,
                          float* __restrict__ canvas) {
    int e = blockIdx.x;
    int b = blockIdx.y;
    int r0 = xyz[(b * NE + e) * 2 + 0] - RR;
    int c0 = xyz[(b * NE + e) * 2 + 1] - RR;
    float sc = 1.0e6f / (psf_sums[e] + 1e-12f);
    float* cb = canvas + (size_t)b * (CAN * CAN);
    for (int p = threadIdx.x; p < PW * PW; p += blockDim.x) {
        int i = p / PW, j = p % PW;
        atomicAdd(cb + (r0 + i) * CAN + (c0 + j), psf[e * PW * PW + p] * sc);
    }
}

// ---------------------------------------------------------------------------
__global__ void k_final(const float* __restrict__ canvas,
                        const float* __restrict__ kern,
                        const float* __restrict__ eps_dark,
                        const float* __restrict__ eps_photon,
                        const float* __restrict__ eps_read,
                        float* __restrict__ out) {
    __shared__ float kk[49];
    __shared__ float tile[14][40];
    int b = blockIdx.z;
    int tx = threadIdx.x, ty = threadIdx.y;
    int t = ty * 32 + tx;
    int j0 = blockIdx.x * 32, i0 = blockIdx.y * 8;
    if (t < 49) kk[t] = kern[t];
    const float* cb = canvas + (size_t)b * (CAN * CAN);
    for (int p = t; p < 14 * 38; p += 256) {
        int rr = p / 38, cc = p % 38;
        int gi = i0 + rr - 2, gj = j0 + cc - 2;
        tile[rr][cc] = (gi >= 0 && gi < CAN && gj >= 0 && gj < CAN)
                           ? cb[gi * CAN + gj] : 0.f;
    }
    __syncthreads();
    int i = i0 + ty, j = j0 + tx;
    if (i >= OHW || j >= OHW) return;
    float acc = 0.f;
#pragma unroll
    for (int a = 0; a < 7; ++a)
#pragma unroll
        for (int q = 0; q < 7; ++q)
            acc += tile[ty + a][tx + q] * kk[a * 7 + q];
    int idx = b * (OHW * OHW) + i * OHW + j;
    float sig = acc * 0.9f;
    float dark = 0.005f + eps_dark[idx] * sqrtf(0.005f);
    float total = fmaxf(sig + dark, 0.0f);
    float noisy = total + eps_photon[idx] * sqrtf(fmaxf(total, 1e-12f));
    float elec = noisy + eps_read[idx] * 1.6f;
    float adu = fminf(fmaxf(elec * 2.0f, 0.0f), 65535.0f);
    float v = (adu <= 10.0f) ? 1.0f : fminf(adu, 4.0e9f);
    out[idx] = v / 4.0e9f;
}

// ---------------------------------------------------------------------------
extern "C" void kernel_launch(void* const* d_in, const int* in_sizes, int n_in,
                              void* d_out, int out_size, void* d_ws, size_t ws_size,
                              hipStream_t stream) {
    const float* phase    = (const float*)d_in[0];
    const float* zs       = (const float*)d_in[1];
    const int*   xyz      = (const int*)d_in[2];
    const float* std_u    = (const float*)d_in[3];
    const float* epsd     = (const float*)d_in[4];
    const float* epsp     = (const float*)d_in[5];
    const float* epsr     = (const float*)d_in[6];
    float* out = (float*)d_out;

    char* ws = (char*)d_ws;
    size_t off = 0;
    auto alloc = [&](size_t bytes) {
        off = (off + 255) & ~(size_t)255;
        size_t o = off; off += bytes; return o;
    };
    float*  kgamma   = (float*) (ws + alloc((size_t)NN * NN * 4));
    float2* tw       = (float2*)(ws + alloc((size_t)NN * 8));
    float2* R1T      = (float2*)(ws + alloc((size_t)NN * NN * 8));
    float2* EfT      = (float2*)(ws + alloc((size_t)NN * NN * 8));
    float2* part     = (float2*)(ws + alloc((size_t)NE * PW * NN * 8));
    float*  psf      = (float*) (ws + alloc((size_t)NE * PW * PW * 4));
    float*  psf_sums = (float*) (ws + alloc((size_t)NE * 4));
    float*  kern     = (float*) (ws + alloc((size_t)64 * 4));
    float*  canvas   = (float*) (ws + alloc((size_t)BATCH * CAN * CAN * 4));
    _Float16* Bg     = (_Float16*)(ws + alloc((size_t)BCH * BG_CHUNK * 2));
    (void)ws_size; (void)n_in; (void)in_sizes; (void)out_size;

    // grid covers max(NN*NN, SETUP_N) = SETUP_N = 320113
    k_setup<<<(SETUP_N + 255) / 256, 256, 0, stream>>>(
        std_u, kgamma, tw, kern, canvas, psf_sums);
    k_setup_b<<<(BCH * 64 * BSTR + 255) / 256, 256, 0, stream>>>(Bg);
    // fft2: rows (fused field gen, writes transposed) then cols (contiguous)
    k_dft_rows<<<NN, 256, 0, stream>>>(phase, R1T, tw);
    k_dft_cols<<<NN, 256, 0, stream>>>(R1T, EfT, tw);
    // partial inverse transforms for the 31x31 crop, all 64 z-planes (MFMA)
    k_prop_mfma<<<NN, 256, 0, stream>>>(EfT, kgamma, zs, Bg, part);
    k_prop_cols<<<dim3(PW, NE), 256, 0, stream>>>(part, psf, psf_sums);
    k_scatter<<<dim3(NE, BATCH), 256, 0, stream>>>(psf, psf_sums, xyz, canvas);
    k_final<<<dim3((OHW + 31) / 32, (OHW + 7) / 8, BATCH), dim3(32, 8), 0, stream>>>(
        canvas, kern, epsd, epsp, epsr, out);
}